// Round 4
// baseline (260.941 us; speedup 1.0000x reference)
//
#include <hip/hip_runtime.h>
#include <math.h>

#define Bn 8
#define Cn 112
#define Hn 64
#define Wn 64
#define On 112
#define Gn 14
#define PGC 378          // 3*G*K2
#define HW 4096          // 64*64
#define CKW 1008         // C*K2 (inner dim)
#define KP 1024          // padded K for pg GEMM
#define NP 384           // padded N (oc) for pg GEMM
#define MHALF 16384      // half-batch pixel count
#define WKP 96           // padded per-group K in deform (k*8+cc, k<12)
#define WROW 192         // bytes per LDS row (96 bf16)
#define PART ((size_t)Bn * On * HW)   // floats per partial

typedef __attribute__((ext_vector_type(8))) short bf16x8;
typedef __attribute__((ext_vector_type(4))) float f32x4;

__device__ __forceinline__ unsigned short f2bf(float f) {
    union { float f; unsigned int u; } v; v.f = f;
    unsigned int r = v.u + 0x7fffu + ((v.u >> 16) & 1u);
    return (unsigned short)(r >> 16);
}
__device__ __forceinline__ float bf2f(unsigned short u) {
    union { unsigned int u; float f; } v; v.u = ((unsigned int)u) << 16;
    return v.f;
}
__device__ __forceinline__ void gload_lds16(const void* g, void* l) {
    __builtin_amdgcn_global_load_lds(
        (const __attribute__((address_space(1))) unsigned int*)g,
        (__attribute__((address_space(3))) unsigned int*)l, 16, 0, 0);
}

// ---------------------------------------------------------------------------
// im2col (half batch) -> A2 bf16 [16384][1024]
// ---------------------------------------------------------------------------
__global__ __launch_bounds__(256) void im2col_kernel(
    const float* __restrict__ x, unsigned short* __restrict__ A2, int half)
{
    int t = blockIdx.x * 256 + threadIdx.x;
    int pxl = t >> 7;
    int ck0 = (t & 127) << 3;
    int pxg = half * MHALF + pxl;
    int b = pxg >> 12, hw = pxg & 4095;
    int h = hw >> 6, ww = hw & 63;
    const float* xb = x + (size_t)b * Cn * HW;

    unsigned short o[8];
    #pragma unroll
    for (int j = 0; j < 8; ++j) {
        int ck = ck0 + j;
        float v = 0.f;
        if (ck < CKW) {
            int c = ck / 9, k = ck - 9 * c;
            int yy = h + k / 3 - 1, xx = ww + (k % 3) - 1;
            if (yy >= 0 && yy < Hn && xx >= 0 && xx < Wn)
                v = xb[c * HW + yy * Wn + xx];
        }
        o[j] = f2bf(v);
    }
    *reinterpret_cast<uint4*>(&A2[(size_t)pxl * KP + ck0]) =
        *reinterpret_cast<const uint4*>(o);
}

// ---------------------------------------------------------------------------
// prep B2 bf16 [384][1024] from pg_weight
// ---------------------------------------------------------------------------
__global__ __launch_bounds__(256) void prep_b_kernel(
    const float* __restrict__ pgw, unsigned short* __restrict__ B2)
{
    int t = blockIdx.x * 256 + threadIdx.x;
    int oc = t >> 10, ck = t & 1023;
    float v = (oc < PGC && ck < CKW) ? pgw[(size_t)oc * CKW + ck] : 0.f;
    B2[t] = f2bf(v);
}

// ---------------------------------------------------------------------------
// prep wbfS: main-conv weights, bf16, [g][oc][k*8+cc] padded to 96,
// pre-swizzled so deform stages linearly and reads with
// byte = (oc*192 + k0*2) ^ ((oc&7)<<4).
// ---------------------------------------------------------------------------
__global__ __launch_bounds__(256) void prep_w_kernel(
    const float* __restrict__ w, unsigned short* __restrict__ wbfS)
{
    int t = blockIdx.x * 256 + threadIdx.x;   // 14*112*96 = 150528
    int g = t / 10752, r = t % 10752;
    int oc = r / 96, ck = r % 96;
    int k = ck >> 3, cc = ck & 7;
    float v = (k < 9) ? w[(size_t)oc * CKW + (g * 8 + cc) * 9 + k] : 0.f;
    int l = oc * 12 + (ck >> 3);
    int c = l ^ (oc & 7);
    wbfS[(size_t)g * 10752 + c * 8 + (ck & 7)] = f2bf(v);
}

// ---------------------------------------------------------------------------
// pg GEMM (validated round 2)
// ---------------------------------------------------------------------------
__global__ __launch_bounds__(256) void pg_gemm_kernel(
    const unsigned short* __restrict__ A2, const unsigned short* __restrict__ B2,
    const float* __restrict__ pgb, unsigned short* __restrict__ pgBF, int half)
{
    __shared__ __align__(16) unsigned short Asm[128 * 32];
    __shared__ __align__(16) unsigned short Bsm[128 * 32];

    const int tid  = threadIdx.x;
    const int lane = tid & 63;
    const int w    = tid >> 6;
    const int wr   = w >> 1, wc = w & 1;
    const int m0   = blockIdx.x * 128;
    const int n0   = blockIdx.y * 128;
    const int fr   = lane & 15, fq = lane >> 4;

    f32x4 acc[4][4] = {};

    const int ldr = lane >> 2;
    const int ldc = (lane & 3) * 8;

    for (int kt = 0; kt < 32; ++kt) {
        if (kt) __syncthreads();
        #pragma unroll
        for (int i = 0; i < 2; ++i) {
            int row = w * 32 + i * 16 + ldr;
            gload_lds16(&A2[(size_t)(m0 + row) * KP + kt * 32 + ldc],
                        &Asm[(w * 32 + i * 16) * 32]);
            gload_lds16(&B2[(size_t)(n0 + row) * KP + kt * 32 + ldc],
                        &Bsm[(w * 32 + i * 16) * 32]);
        }
        __syncthreads();

        bf16x8 a[4], b[4];
        #pragma unroll
        for (int mi = 0; mi < 4; ++mi)
            a[mi] = *reinterpret_cast<const bf16x8*>(
                &Asm[(wr * 64 + mi * 16 + fr) * 32 + fq * 8]);
        #pragma unroll
        for (int ni = 0; ni < 4; ++ni)
            b[ni] = *reinterpret_cast<const bf16x8*>(
                &Bsm[(wc * 64 + ni * 16 + fr) * 32 + fq * 8]);
        #pragma unroll
        for (int mi = 0; mi < 4; ++mi)
            #pragma unroll
            for (int ni = 0; ni < 4; ++ni)
                acc[mi][ni] = __builtin_amdgcn_mfma_f32_16x16x32_bf16(
                    a[mi], b[ni], acc[mi][ni], 0, 0, 0);
    }

    #pragma unroll
    for (int ni = 0; ni < 4; ++ni) {
        int oc = n0 + wc * 64 + ni * 16 + fr;
        if (oc >= PGC) continue;
        float bias = pgb[oc];
        #pragma unroll
        for (int mi = 0; mi < 4; ++mi) {
            int pxl = m0 + wr * 64 + mi * 16 + fq * 4;
            int pxg = half * MHALF + pxl;
            int b = pxg >> 12, hw = pxg & 4095;
            ushort4 pk;
            pk.x = f2bf(acc[mi][ni][0] + bias);
            pk.y = f2bf(acc[mi][ni][1] + bias);
            pk.z = f2bf(acc[mi][ni][2] + bias);
            pk.w = f2bf(acc[mi][ni][3] + bias);
            *reinterpret_cast<ushort4*>(
                &pgBF[((size_t)(b * PGC + oc)) * HW + hw]) = pk;
        }
    }
}

// ---------------------------------------------------------------------------
// deform: block = (y, b, chunk); 7 groups per block; partial accumulate.
// Sampling: thread = (px = w*16+(lane&15), cpair q = lane>>4);
// 9 taps fully unrolled x 2 channels -> even load, deep ILP.
// MFMA: wave w owns px-tile [w*16,w*16+16), 7 oc-tiles, K=96.
// ---------------------------------------------------------------------------
__global__ __launch_bounds__(256, 4) void deform_kernel(
    const float* __restrict__ x, const unsigned short* __restrict__ pg,
    const unsigned short* __restrict__ wbfS, float* __restrict__ P)
{
    __shared__ __align__(16) unsigned short wt[Cn * WKP];    // 21504 B
    __shared__ __align__(16) unsigned short smp[64 * WKP];   // 12288 B

    const int tid   = threadIdx.x;
    const int lane  = tid & 63;
    const int w     = tid >> 6;
    const int y     = blockIdx.x;
    const int b     = blockIdx.y;
    const int chunk = blockIdx.z;

    // zero the pad taps (k=9..11)
    if (tid < 64) {
        const uint4 z = {0, 0, 0, 0};
        #pragma unroll
        for (int k = 9; k < 12; ++k) {
            int byte = (tid * WROW + k * 16) ^ ((tid & 7) << 4);
            *reinterpret_cast<uint4*>(reinterpret_cast<char*>(smp) + byte) = z;
        }
    }

    f32x4 acc[7] = {};

    const int px = w * 16 + (lane & 15);   // sampling pixel
    const int q  = lane >> 4;              // channel pair (2q, 2q+1)

    const unsigned short* pgk = pg + (size_t)b * PGC * HW + y * 64 + px;
    const float* xb = x + (size_t)b * Cn * HW;

    for (int gi = 0; gi < 7; ++gi) {
        const int g = chunk * 7 + gi;

        // stage weights (async, drains at the barrier)
        const char* src = (const char*)wbfS + (size_t)g * (Cn * WKP * 2);
        for (int wi = w; wi < 21; wi += 4)
            gload_lds16(src + (size_t)(wi * 64 + lane) * 16,
                        (char*)wt + wi * 1024);

        const float* img0 = xb + (size_t)(g * 8 + 2 * q) * HW;
        const float* img1 = img0 + HW;

        #pragma unroll
        for (int k = 0; k < 9; ++k) {
            const int ky = k / 3, kx = k % 3;
            float dy = bf2f(pgk[(size_t)(18 * g + 2 * k) * HW]);
            float dx = bf2f(pgk[(size_t)(18 * g + 2 * k + 1) * HW]);
            float mv = bf2f(pgk[(size_t)(252 + 9 * g + k) * HW]);
            float m  = 1.f / (1.f + __expf(-mv));

            float yf = (float)(y + ky - 1) + dy;
            float xf = (float)(px + kx - 1) + dx;
            float y0 = floorf(yf), x0 = floorf(xf);
            float wy1 = yf - y0, wx1 = xf - x0;
            float wy0 = 1.f - wy1, wx0 = 1.f - wx1;
            int iy0 = (int)y0, ix0 = (int)x0;
            bool vy0 = (iy0 >= 0) && (iy0 < Hn);
            bool vy1 = (iy0 >= -1) && (iy0 < Hn - 1);
            bool vx0 = (ix0 >= 0) && (ix0 < Wn);
            bool vx1 = (ix0 >= -1) && (ix0 < Wn - 1);
            int cy0 = min(max(iy0, 0), Hn - 1), cy1 = min(max(iy0 + 1, 0), Hn - 1);
            int cx0 = min(max(ix0, 0), Wn - 1), cx1 = min(max(ix0 + 1, 0), Wn - 1);
            float w00 = (vy0 && vx0) ? wy0 * wx0 * m : 0.f;
            float w01 = (vy0 && vx1) ? wy0 * wx1 * m : 0.f;
            float w10 = (vy1 && vx0) ? wy1 * wx0 * m : 0.f;
            float w11 = (vy1 && vx1) ? wy1 * wx1 * m : 0.f;
            int i00 = cy0 * Wn + cx0, i01 = cy0 * Wn + cx1;
            int i10 = cy1 * Wn + cx0, i11 = cy1 * Wn + cx1;

            float a0 = img0[i00], a1 = img0[i01], a2 = img0[i10], a3 = img0[i11];
            float b0 = img1[i00], b1 = img1[i01], b2 = img1[i10], b3 = img1[i11];
            float v0 = a0 * w00 + a1 * w01 + a2 * w10 + a3 * w11;
            float v1 = b0 * w00 + b1 * w01 + b2 * w10 + b3 * w11;
            unsigned int pk = (unsigned int)f2bf(v0) |
                              ((unsigned int)f2bf(v1) << 16);
            int byte = (px * WROW + k * 16 + q * 4) ^ ((px & 7) << 4);
            *reinterpret_cast<unsigned int*>(
                reinterpret_cast<char*>(smp) + byte) = pk;
        }
        __syncthreads();

        // MFMA GEMM
        const int pxl = w * 16 + (lane & 15);
        const int ocl = lane & 15;
        #pragma unroll
        for (int ch = 0; ch < 3; ++ch) {
            const int k0 = ch * 32 + (lane >> 4) * 8;
            int bbyte = (pxl * WROW + k0 * 2) ^ ((pxl & 7) << 4);
            bf16x8 bfrag = *reinterpret_cast<const bf16x8*>(
                reinterpret_cast<const char*>(smp) + bbyte);
            #pragma unroll
            for (int t2 = 0; t2 < 7; ++t2) {
                int oc = t2 * 16 + ocl;
                int abyte = (oc * WROW + k0 * 2) ^ ((oc & 7) << 4);
                bf16x8 afrag = *reinterpret_cast<const bf16x8*>(
                    reinterpret_cast<const char*>(wt) + abyte);
                acc[t2] = __builtin_amdgcn_mfma_f32_16x16x32_bf16(
                    afrag, bfrag, acc[t2], 0, 0, 0);
            }
        }
        __syncthreads();
    }

    const int pxl = w * 16 + (lane & 15);
    const int fq  = lane >> 4;
    float* pb = P + (((size_t)chunk * Bn + b) * On) * HW + y * 64 + pxl;
    #pragma unroll
    for (int t2 = 0; t2 < 7; ++t2) {
        #pragma unroll
        for (int r = 0; r < 4; ++r) {
            int oc = t2 * 16 + fq * 4 + r;
            pb[(size_t)oc * HW] = acc[t2][r];
        }
    }
}

// ---------------------------------------------------------------------------
// combine: out = P0 + P1 + bias
// ---------------------------------------------------------------------------
__global__ __launch_bounds__(256) void combine_kernel(
    const float* __restrict__ P, const float* __restrict__ bias,
    float* __restrict__ out)
{
    int i = blockIdx.x * 256 + threadIdx.x;   // float4 units, 917504 total
    float4 a = reinterpret_cast<const float4*>(P)[i];
    float4 c = reinterpret_cast<const float4*>(P + PART)[i];
    int oc = (i >> 10) % On;
    float bv = bias[oc];
    float4 o;
    o.x = a.x + c.x + bv; o.y = a.y + c.y + bv;
    o.z = a.z + c.z + bv; o.w = a.w + c.w + bv;
    reinterpret_cast<float4*>(out)[i] = o;
}

// ---------------------------------------------------------------------------
extern "C" void kernel_launch(void* const* d_in, const int* in_sizes, int n_in,
                              void* d_out, int out_size, void* d_ws, size_t ws_size,
                              hipStream_t stream) {
    const float* x    = (const float*)d_in[0];
    const float* pgw  = (const float*)d_in[1];
    const float* pgb  = (const float*)d_in[2];
    const float* w    = (const float*)d_in[3];
    const float* bias = (const float*)d_in[4];
    float* out = (float*)d_out;

    char* wsb = (char*)d_ws;
    unsigned short* pgBF = (unsigned short*)wsb;                       // 24.77 MB
    size_t off = (size_t)PGC * Bn * HW * 2;
    unsigned short* B2   = (unsigned short*)(wsb + off);               // 0.79 MB
    off += (size_t)NP * KP * 2;
    unsigned short* A2   = (unsigned short*)(wsb + off);               // 33.55 MB
    float* P             = (float*)(wsb + off);                        // 29.36 MB (over A2, dead after pg_gemm)
    off += (size_t)MHALF * KP * 2;
    unsigned short* wbfS = (unsigned short*)(wsb + off);               // 0.30 MB

    prep_b_kernel<<<NP * KP / 256, 256, 0, stream>>>(pgw, B2);
    prep_w_kernel<<<(Gn * Cn * WKP) / 256, 256, 0, stream>>>(w, wbfS);

    for (int half = 0; half < 2; ++half) {
        im2col_kernel<<<MHALF * 128 / 256, 256, 0, stream>>>(x, A2, half);
        dim3 gg(MHALF / 128, NP / 128);
        pg_gemm_kernel<<<gg, 256, 0, stream>>>(A2, B2, pgb, pgBF, half);
    }

    dim3 gD(Hn, Bn, 2);
    deform_kernel<<<gD, 256, 0, stream>>>(x, pgBF, wbfS, P);

    combine_kernel<<<(Bn * On * HW / 4) / 256, 256, 0, stream>>>(P, bias, out);
}

// Round 5
// 215.851 us; speedup vs baseline: 1.2089x; 1.2089x over previous
//
#include <hip/hip_runtime.h>
#include <math.h>

#define Bn 8
#define Cn 112
#define Hn 64
#define Wn 64
#define On 112
#define Gn 14
#define PGC 378          // 3*G*K2
#define HW 4096          // 64*64
#define CKW 1008         // C*K2 (inner dim)
#define KP 1024          // padded K for pg GEMM
#define NP 384           // padded N (oc) for pg GEMM
#define MFULL 32768      // full-batch pixel count
#define MHALF 16384      // half-batch pixel count
#define WKP 96           // padded per-group K in deform (k*8+cc, k<12)
#define WROW 192         // bytes per LDS row (96 bf16)
#define PART ((size_t)Bn * On * HW)   // floats per partial

typedef __attribute__((ext_vector_type(8))) short bf16x8;
typedef __attribute__((ext_vector_type(4))) float f32x4;

__device__ __forceinline__ unsigned short f2bf(float f) {
    union { float f; unsigned int u; } v; v.f = f;
    unsigned int r = v.u + 0x7fffu + ((v.u >> 16) & 1u);
    return (unsigned short)(r >> 16);
}
__device__ __forceinline__ float bf2f(unsigned short u) {
    union { unsigned int u; float f; } v; v.u = ((unsigned int)u) << 16;
    return v.f;
}
__device__ __forceinline__ void gload_lds16(const void* g, void* l) {
    __builtin_amdgcn_global_load_lds(
        (const __attribute__((address_space(1))) unsigned int*)g,
        (__attribute__((address_space(3))) unsigned int*)l, 16, 0, 0);
}

// ---------------------------------------------------------------------------
// im2col -> A2 bf16 [count][1024], pixel range [px_base, px_base+count)
// ---------------------------------------------------------------------------
__global__ __launch_bounds__(256) void im2col_kernel(
    const float* __restrict__ x, unsigned short* __restrict__ A2, int px_base)
{
    int t = blockIdx.x * 256 + threadIdx.x;
    int pxl = t >> 7;
    int ck0 = (t & 127) << 3;
    int pxg = px_base + pxl;
    int b = pxg >> 12, hw = pxg & 4095;
    int h = hw >> 6, ww = hw & 63;
    const float* xb = x + (size_t)b * Cn * HW;

    unsigned short o[8];
    #pragma unroll
    for (int j = 0; j < 8; ++j) {
        int ck = ck0 + j;
        float v = 0.f;
        if (ck < CKW) {
            int c = ck / 9, k = ck - 9 * c;
            int yy = h + k / 3 - 1, xx = ww + (k % 3) - 1;
            if (yy >= 0 && yy < Hn && xx >= 0 && xx < Wn)
                v = xb[c * HW + yy * Wn + xx];
        }
        o[j] = f2bf(v);
    }
    *reinterpret_cast<uint4*>(&A2[(size_t)pxl * KP + ck0]) =
        *reinterpret_cast<const uint4*>(o);
}

// ---------------------------------------------------------------------------
// prep B2 bf16 [384][1024] from pg_weight
// ---------------------------------------------------------------------------
__global__ __launch_bounds__(256) void prep_b_kernel(
    const float* __restrict__ pgw, unsigned short* __restrict__ B2)
{
    int t = blockIdx.x * 256 + threadIdx.x;
    int oc = t >> 10, ck = t & 1023;
    float v = (oc < PGC && ck < CKW) ? pgw[(size_t)oc * CKW + ck] : 0.f;
    B2[t] = f2bf(v);
}

// ---------------------------------------------------------------------------
// prep wbfS: main-conv weights, bf16, [g][oc][k*8+cc] padded to 96,
// pre-swizzled so deform stages linearly and reads with
// byte = (oc*192 + koff*2) ^ ((oc&7)<<4).
// ---------------------------------------------------------------------------
__global__ __launch_bounds__(256) void prep_w_kernel(
    const float* __restrict__ w, unsigned short* __restrict__ wbfS)
{
    int t = blockIdx.x * 256 + threadIdx.x;   // 14*112*96 = 150528
    int g = t / 10752, r = t % 10752;
    int oc = r / 96, ck = r % 96;
    int k = ck >> 3, cc = ck & 7;
    float v = (k < 9) ? w[(size_t)oc * CKW + (g * 8 + cc) * 9 + k] : 0.f;
    int l = oc * 12 + (ck >> 3);
    int c = l ^ (oc & 7);
    wbfS[(size_t)g * 10752 + c * 8 + (ck & 7)] = f2bf(v);
}

// ---------------------------------------------------------------------------
// pg GEMM  (m97 structure, validated rounds 2-4); px_base selects range
// ---------------------------------------------------------------------------
__global__ __launch_bounds__(256) void pg_gemm_kernel(
    const unsigned short* __restrict__ A2, const unsigned short* __restrict__ B2,
    const float* __restrict__ pgb, unsigned short* __restrict__ pgBF, int px_base)
{
    __shared__ __align__(16) unsigned short Asm[128 * 32];
    __shared__ __align__(16) unsigned short Bsm[128 * 32];

    const int tid  = threadIdx.x;
    const int lane = tid & 63;
    const int w    = tid >> 6;
    const int wr   = w >> 1, wc = w & 1;
    const int m0   = blockIdx.x * 128;
    const int n0   = blockIdx.y * 128;
    const int fr   = lane & 15, fq = lane >> 4;

    f32x4 acc[4][4] = {};

    const int ldr = lane >> 2;
    const int ldc = (lane & 3) * 8;

    for (int kt = 0; kt < 32; ++kt) {
        if (kt) __syncthreads();
        #pragma unroll
        for (int i = 0; i < 2; ++i) {
            int row = w * 32 + i * 16 + ldr;
            gload_lds16(&A2[(size_t)(m0 + row) * KP + kt * 32 + ldc],
                        &Asm[(w * 32 + i * 16) * 32]);
            gload_lds16(&B2[(size_t)(n0 + row) * KP + kt * 32 + ldc],
                        &Bsm[(w * 32 + i * 16) * 32]);
        }
        __syncthreads();

        bf16x8 a[4], b[4];
        #pragma unroll
        for (int mi = 0; mi < 4; ++mi)
            a[mi] = *reinterpret_cast<const bf16x8*>(
                &Asm[(wr * 64 + mi * 16 + fr) * 32 + fq * 8]);
        #pragma unroll
        for (int ni = 0; ni < 4; ++ni)
            b[ni] = *reinterpret_cast<const bf16x8*>(
                &Bsm[(wc * 64 + ni * 16 + fr) * 32 + fq * 8]);
        #pragma unroll
        for (int mi = 0; mi < 4; ++mi)
            #pragma unroll
            for (int ni = 0; ni < 4; ++ni)
                acc[mi][ni] = __builtin_amdgcn_mfma_f32_16x16x32_bf16(
                    a[mi], b[ni], acc[mi][ni], 0, 0, 0);
    }

    #pragma unroll
    for (int ni = 0; ni < 4; ++ni) {
        int oc = n0 + wc * 64 + ni * 16 + fr;
        if (oc >= PGC) continue;
        float bias = pgb[oc];
        #pragma unroll
        for (int mi = 0; mi < 4; ++mi) {
            int pxl = m0 + wr * 64 + mi * 16 + fq * 4;
            int pxg = px_base + pxl;
            int b = pxg >> 12, hw = pxg & 4095;
            ushort4 pk;
            pk.x = f2bf(acc[mi][ni][0] + bias);
            pk.y = f2bf(acc[mi][ni][1] + bias);
            pk.z = f2bf(acc[mi][ni][2] + bias);
            pk.w = f2bf(acc[mi][ni][3] + bias);
            *reinterpret_cast<ushort4*>(
                &pgBF[((size_t)(b * PGC + oc)) * HW + hw]) = pk;
        }
    }
}

// ---------------------------------------------------------------------------
// one deformable tap: all 8 channels, 32 gathers batched in registers,
// bilinear reduce, one ds_write_b128 into swizzled smp
// ---------------------------------------------------------------------------
__device__ __forceinline__ void sample_tap(
    int k, float dy, float dx, float mv,
    const float* __restrict__ xg, int y, int px,
    unsigned short* __restrict__ smp)
{
    const int ky = k / 3, kx = k % 3;
    float m = 1.f / (1.f + __expf(-mv));

    float yf = (float)(y + ky - 1) + dy;
    float xf = (float)(px + kx - 1) + dx;
    float y0 = floorf(yf), x0 = floorf(xf);
    float wy1 = yf - y0, wx1 = xf - x0;
    float wy0 = 1.f - wy1, wx0 = 1.f - wx1;
    int iy0 = (int)y0, ix0 = (int)x0;
    bool vy0 = (iy0 >= 0) && (iy0 < Hn);
    bool vy1 = (iy0 >= -1) && (iy0 < Hn - 1);
    bool vx0 = (ix0 >= 0) && (ix0 < Wn);
    bool vx1 = (ix0 >= -1) && (ix0 < Wn - 1);
    int cy0 = min(max(iy0, 0), Hn - 1), cy1 = min(max(iy0 + 1, 0), Hn - 1);
    int cx0 = min(max(ix0, 0), Wn - 1), cx1 = min(max(ix0 + 1, 0), Wn - 1);
    float w00 = (vy0 && vx0) ? wy0 * wx0 * m : 0.f;
    float w01 = (vy0 && vx1) ? wy0 * wx1 * m : 0.f;
    float w10 = (vy1 && vx0) ? wy1 * wx0 * m : 0.f;
    float w11 = (vy1 && vx1) ? wy1 * wx1 * m : 0.f;
    int i00 = cy0 * Wn + cx0, i01 = cy0 * Wn + cx1;
    int i10 = cy1 * Wn + cx0, i11 = cy1 * Wn + cx1;

    // 32 independent gathers, all in flight before the reduction
    float v[8][4];
    #pragma unroll
    for (int c = 0; c < 8; ++c) {
        const float* img = xg + (size_t)c * HW;
        v[c][0] = img[i00]; v[c][1] = img[i01];
        v[c][2] = img[i10]; v[c][3] = img[i11];
    }
    unsigned int pk[4];
    #pragma unroll
    for (int c2 = 0; c2 < 4; ++c2) {
        float v0 = v[2*c2][0]*w00 + v[2*c2][1]*w01 + v[2*c2][2]*w10 + v[2*c2][3]*w11;
        float v1 = v[2*c2+1][0]*w00 + v[2*c2+1][1]*w01 + v[2*c2+1][2]*w10 + v[2*c2+1][3]*w11;
        pk[c2] = (unsigned int)f2bf(v0) | ((unsigned int)f2bf(v1) << 16);
    }
    int byte = (px * WROW + k * 16) ^ ((px & 7) << 4);
    *reinterpret_cast<uint4*>(reinterpret_cast<char*>(smp) + byte) =
        *reinterpret_cast<const uint4*>(pk);
}

// ---------------------------------------------------------------------------
// deform: block = (y, b, chunk of 7 groups); 4 waves.
// Sampling tasks: wave w handles taps {w, w+4} (+{8} for wave 0), px = lane.
// pg values prefetched per group; gathers batched 32-deep per tap.
// MFMA: wave w owns px-tile [w*16,w*16+16), 7 oc-tiles, K=96.
// ---------------------------------------------------------------------------
__global__ __launch_bounds__(256, 4) void deform_kernel(
    const float* __restrict__ x, const unsigned short* __restrict__ pg,
    const unsigned short* __restrict__ wbfS, float* __restrict__ P)
{
    __shared__ __align__(16) unsigned short wt[Cn * WKP];    // 21504 B
    __shared__ __align__(16) unsigned short smp[64 * WKP];   // 12288 B

    const int tid   = threadIdx.x;
    const int lane  = tid & 63;
    const int w     = tid >> 6;
    const int y     = blockIdx.x;
    const int b     = blockIdx.y;
    const int chunk = blockIdx.z;
    const int px    = lane;

    // zero the pad taps (k=9..11) — guards against stale NaN bits in LDS
    if (tid < 64) {
        const uint4 z = {0, 0, 0, 0};
        #pragma unroll
        for (int k = 9; k < 12; ++k) {
            int byte = (tid * WROW + k * 16) ^ ((tid & 7) << 4);
            *reinterpret_cast<uint4*>(reinterpret_cast<char*>(smp) + byte) = z;
        }
    }

    f32x4 acc[7] = {};

    const unsigned short* pgk = pg + (size_t)b * PGC * HW + y * 64 + px;
    const float* xb = x + (size_t)b * Cn * HW;
    const int k0 = w, k1 = w + 4;

    for (int gi = 0; gi < 7; ++gi) {
        const int g = chunk * 7 + gi;

        // stage weights (async, drains at the barrier)
        const char* src = (const char*)wbfS + (size_t)g * (Cn * WKP * 2);
        for (int wi = w; wi < 21; wi += 4)
            gload_lds16(src + (size_t)(wi * 64 + lane) * 16,
                        (char*)wt + wi * 1024);

        const float* xg = xb + (size_t)(g * 8) * HW;

        // prefetch pg for my taps: 6 (or 9) independent loads
        const unsigned short* pgo = pgk + (size_t)(18 * g) * HW;
        const unsigned short* pgm = pgk + (size_t)(252 + 9 * g) * HW;
        float dy0 = bf2f(pgo[(size_t)(2 * k0) * HW]);
        float dx0 = bf2f(pgo[(size_t)(2 * k0 + 1) * HW]);
        float dy1 = bf2f(pgo[(size_t)(2 * k1) * HW]);
        float dx1 = bf2f(pgo[(size_t)(2 * k1 + 1) * HW]);
        float mv0 = bf2f(pgm[(size_t)k0 * HW]);
        float mv1 = bf2f(pgm[(size_t)k1 * HW]);
        float dy2 = 0.f, dx2 = 0.f, mv2 = 0.f;
        if (w == 0) {
            dy2 = bf2f(pgo[(size_t)16 * HW]);
            dx2 = bf2f(pgo[(size_t)17 * HW]);
            mv2 = bf2f(pgm[(size_t)8 * HW]);
        }

        sample_tap(k0, dy0, dx0, mv0, xg, y, px, smp);
        sample_tap(k1, dy1, dx1, mv1, xg, y, px, smp);
        if (w == 0)
            sample_tap(8, dy2, dx2, mv2, xg, y, px, smp);
        __syncthreads();

        // MFMA GEMM
        const int pxl = w * 16 + (lane & 15);
        const int ocl = lane & 15;
        #pragma unroll
        for (int ch = 0; ch < 3; ++ch) {
            const int koff = ch * 32 + (lane >> 4) * 8;
            int bbyte = (pxl * WROW + koff * 2) ^ ((pxl & 7) << 4);
            bf16x8 bfrag = *reinterpret_cast<const bf16x8*>(
                reinterpret_cast<const char*>(smp) + bbyte);
            #pragma unroll
            for (int t2 = 0; t2 < 7; ++t2) {
                int oc = t2 * 16 + ocl;
                int abyte = (oc * WROW + koff * 2) ^ ((oc & 7) << 4);
                bf16x8 afrag = *reinterpret_cast<const bf16x8*>(
                    reinterpret_cast<const char*>(wt) + abyte);
                acc[t2] = __builtin_amdgcn_mfma_f32_16x16x32_bf16(
                    afrag, bfrag, acc[t2], 0, 0, 0);
            }
        }
        __syncthreads();
    }

    const int pxl = w * 16 + (lane & 15);
    const int fq  = lane >> 4;
    float* pb = P + (((size_t)chunk * Bn + b) * On) * HW + y * 64 + pxl;
    #pragma unroll
    for (int t2 = 0; t2 < 7; ++t2) {
        #pragma unroll
        for (int r = 0; r < 4; ++r) {
            int oc = t2 * 16 + fq * 4 + r;
            pb[(size_t)oc * HW] = acc[t2][r];
        }
    }
}

// ---------------------------------------------------------------------------
// combine: out = P0 + P1 + bias
// ---------------------------------------------------------------------------
__global__ __launch_bounds__(256) void combine_kernel(
    const float* __restrict__ P, const float* __restrict__ bias,
    float* __restrict__ out)
{
    int i = blockIdx.x * 256 + threadIdx.x;   // float4 units, 917504 total
    float4 a = reinterpret_cast<const float4*>(P)[i];
    float4 c = reinterpret_cast<const float4*>(P + PART)[i];
    int oc = (i >> 10) % On;
    float bv = bias[oc];
    float4 o;
    o.x = a.x + c.x + bv; o.y = a.y + c.y + bv;
    o.z = a.z + c.z + bv; o.w = a.w + c.w + bv;
    reinterpret_cast<float4*>(out)[i] = o;
}

// ---------------------------------------------------------------------------
extern "C" void kernel_launch(void* const* d_in, const int* in_sizes, int n_in,
                              void* d_out, int out_size, void* d_ws, size_t ws_size,
                              hipStream_t stream) {
    const float* x    = (const float*)d_in[0];
    const float* pgw  = (const float*)d_in[1];
    const float* pgb  = (const float*)d_in[2];
    const float* w    = (const float*)d_in[3];
    const float* bias = (const float*)d_in[4];
    float* out = (float*)d_out;

    char* wsb = (char*)d_ws;
    unsigned short* pgBF = (unsigned short*)wsb;                       // 24.77 MB
    size_t off = (size_t)PGC * Bn * HW * 2;
    unsigned short* B2   = (unsigned short*)(wsb + off);               // 0.79 MB
    off += (size_t)NP * KP * 2;
    unsigned short* wbfS = (unsigned short*)(wsb + off);               // 0.30 MB
    off += (size_t)Gn * Cn * WKP * 2;
    unsigned short* A2   = (unsigned short*)(wsb + off);               // 67.1 MB (full) / 33.6 MB (half)
    float* P             = (float*)A2;  // 29.36 MB, A2 dead after pg_gemm

    const bool full = ws_size >= off + (size_t)MFULL * KP * 2;

    prep_b_kernel<<<NP * KP / 256, 256, 0, stream>>>(pgw, B2);
    prep_w_kernel<<<(Gn * Cn * WKP) / 256, 256, 0, stream>>>(w, wbfS);

    if (full) {
        im2col_kernel<<<MFULL * 128 / 256, 256, 0, stream>>>(x, A2, 0);
        dim3 gg(MFULL / 128, NP / 128);
        pg_gemm_kernel<<<gg, 256, 0, stream>>>(A2, B2, pgb, pgBF, 0);
    } else {
        for (int half = 0; half < 2; ++half) {
            im2col_kernel<<<MHALF * 128 / 256, 256, 0, stream>>>(x, A2, half * MHALF);
            dim3 gg(MHALF / 128, NP / 128);
            pg_gemm_kernel<<<gg, 256, 0, stream>>>(A2, B2, pgb, pgBF, half * MHALF);
        }
    }

    dim3 gD(Hn, Bn, 2);
    deform_kernel<<<gD, 256, 0, stream>>>(x, pgBF, wbfS, P);

    combine_kernel<<<(Bn * On * HW / 4) / 256, 256, 0, stream>>>(P, bias, out);
}